// Round 10
// baseline (776.581 us; speedup 1.0000x reference)
//
#include <hip/hip_runtime.h>

#define N_NODES 50000
#define N_EDGES 1600000
#define D_IN 192
#define D_HID 128

#define NSLICE 8
#define SLICE_SZ ((N_NODES + NSLICE - 1) / NSLICE)   // 6250 (dst slices for fill)

#define CAP 96                                        // fixed slots per node
#define NW_TOTAL 114688                               // Wt arena ushorts
#define DHIS_BLOCKS ((N_NODES + 255) / 256)           // 196

typedef __bf16 bf16x8 __attribute__((ext_vector_type(8)));
typedef float f32x4 __attribute__((ext_vector_type(4)));
typedef float f32x2 __attribute__((ext_vector_type(2)));
typedef unsigned short u16x8 __attribute__((ext_vector_type(8)));

__device__ __forceinline__ unsigned short f2b(float x) {
    unsigned u = __builtin_bit_cast(unsigned, x);
    u += 0x7FFFu + ((u >> 16) & 1u);          // round-to-nearest-even
    return (unsigned short)(u >> 16);
}
__device__ __forceinline__ float blo(unsigned u) {   // low bf16 of packed pair
    return __builtin_bit_cast(float, u << 16);
}
__device__ __forceinline__ float bhi(unsigned u) {   // high bf16
    return __builtin_bit_cast(float, u & 0xFFFF0000u);
}
__device__ __forceinline__ bf16x8 pack8(float4 a, float4 b) {
    u16x8 t;
    t[0] = f2b(a.x); t[1] = f2b(a.y); t[2] = f2b(a.z); t[3] = f2b(a.w);
    t[4] = f2b(b.x); t[5] = f2b(b.y); t[6] = f2b(b.z); t[7] = f2b(b.w);
    return __builtin_bit_cast(bf16x8, t);
}

// ---------------- prep: weight transpose + zero cnt ----------------

__global__ __launch_bounds__(256) void prep_zero(
        const float* __restrict__ W1, const float* __restrict__ W4,
        const float* __restrict__ W2, const float* __restrict__ W3,
        const float* __restrict__ W5, const float* __restrict__ W6,
        unsigned short* __restrict__ Wt, int* __restrict__ cnt) {
    int idx = blockIdx.x * 256 + threadIdx.x;
    if (idx < N_NODES) cnt[idx] = 0;
    if (idx < NW_TOTAL) {
        const float* W; int K, base;
        if      (idx <  24576) { W = W1; K = 192; base = 0; }
        else if (idx <  49152) { W = W4; K = 192; base = 24576; }
        else if (idx <  65536) { W = W2; K = 128; base = 49152; }
        else if (idx <  81920) { W = W3; K = 128; base = 65536; }
        else if (idx <  98304) { W = W5; K = 128; base = 81920; }
        else                   { W = W6; K = 128; base = 98304; }
        int r = idx - base;
        int j = r / K, k = r - j * K;
        Wt[idx] = f2b(W[(size_t)k * 128 + j]);
    }
}

// ---------------- hist + per-edge rank (slot uniqueness only) ----------------

__global__ void hist_kernel(const int* __restrict__ dst, int E,
                            int* __restrict__ cnt, int* __restrict__ rank) {
    int e = blockIdx.x * blockDim.x + threadIdx.x;
    if (e < E) rank[e] = atomicAdd(&cnt[dst[e]], 1);
}

// ---------------- slice-partitioned scatter into fixed-stride rows ----------
// slot = d*CAP + rank[e]; no scan, no row_ptr. Blocks [0,196) also emit dhis.

__global__ __launch_bounds__(256) void fill_sliced(
        const int* __restrict__ src, const int* __restrict__ dst,
        const int* __restrict__ rank, const int* __restrict__ cnt,
        float* __restrict__ dhis, int* __restrict__ esrc, int E, int nchunks) {
    if (blockIdx.x < DHIS_BLOCKS) {
        int i = blockIdx.x * 256 + threadIdx.x;
        if (i < N_NODES) dhis[i] = rsqrtf((float)cnt[i] + 1.0f);
    }
    int slice = blockIdx.x & (NSLICE - 1);
    int chunk = blockIdx.x >> 3;
    int lo = slice * SLICE_SZ;
    int hi = lo + SLICE_SZ;
    int per = (E + nchunks - 1) / nchunks;
    int e0 = chunk * per;
    int e1 = min(e0 + per, E);
    for (int e = e0 + threadIdx.x; e < e1; e += 256) {
        int d = dst[e];
        if (d >= lo && d < hi) {
            esrc[d * CAP + rank[e]] = src[e];
        }
    }
}

// ---------------- dual-view MFMA GEMM ----------------
// Block 256 thr = 4 waves, BM=128 (32 rows/wave, 2 row-frags). grid.y = view.
// B staged once into LDS in fragment-linear order (conflict-free b128 reads).
// A global->register per wave. Out interleaved: ci = (col>>1)*4+view*2+(col&1).

__global__ __launch_bounds__(256) void gemm_dual(
        const float* __restrict__ A0, const float* __restrict__ A1, int lda,
        int K, int ns,
        const unsigned short* __restrict__ Wt0, const unsigned short* __restrict__ Wt1,
        const float* __restrict__ bias0, const float* __restrict__ bias1,
        unsigned short* __restrict__ out, int M) {
    __shared__ __align__(16) unsigned short Wlds[192 * 128];   // up to 48 KB

    int view = blockIdx.y;
    const float* A = view ? A1 : A0;
    const unsigned short* Wt = view ? Wt1 : Wt0;
    const float* bias = view ? bias1 : bias0;

    int tid = threadIdx.x;

    int nfrag = ns * 512;
    for (int f = tid; f < nfrag; f += 256) {
        int lane = f & 63;
        int gk = f >> 6;
        int g = gk / ns, ks = gk - g * ns;
        int col = g * 16 + (lane & 15);
        int kpos = ks * 32 + (lane >> 4) * 8;
        *(bf16x8*)(Wlds + (size_t)f * 8) =
            *(const bf16x8*)(Wt + (size_t)col * K + kpos);
    }
    __syncthreads();

    int wave = tid >> 6, lane = tid & 63;
    int m = lane & 15, quad = lane >> 4;
    int row0 = blockIdx.x * 128;

    int rA0 = row0 + wave * 32 + m;
    int rA1 = rA0 + 16;
    int cA0 = rA0 < M ? rA0 : M - 1;
    int cA1 = rA1 < M ? rA1 : M - 1;
    const float* a0 = A + (size_t)cA0 * lda + quad * 8;
    const float* a1 = A + (size_t)cA1 * lda + quad * 8;

    f32x4 acc[2][8];
#pragma unroll
    for (int h = 0; h < 2; ++h)
#pragma unroll
        for (int g = 0; g < 8; ++g) acc[h][g] = (f32x4){0.f, 0.f, 0.f, 0.f};

    const bf16x8* wl = (const bf16x8*)Wlds;
    for (int ks = 0; ks < ns; ++ks) {
        float4 va = *(const float4*)(a0 + ks * 32);
        float4 vb = *(const float4*)(a0 + ks * 32 + 4);
        float4 vc = *(const float4*)(a1 + ks * 32);
        float4 vd = *(const float4*)(a1 + ks * 32 + 4);
        bf16x8 af0 = pack8(va, vb);
        bf16x8 af1 = pack8(vc, vd);
#pragma unroll
        for (int g = 0; g < 8; ++g) {
            bf16x8 bfr = wl[(g * ns + ks) * 64 + lane];
            acc[0][g] = __builtin_amdgcn_mfma_f32_16x16x32_bf16(af0, bfr, acc[0][g], 0, 0, 0);
            acc[1][g] = __builtin_amdgcn_mfma_f32_16x16x32_bf16(af1, bfr, acc[1][g], 0, 0, 0);
        }
    }

#pragma unroll
    for (int h = 0; h < 2; ++h) {
#pragma unroll
        for (int g = 0; g < 8; ++g) {
            int col = g * 16 + m;
            float bv = bias[col];
            int ci = ((col >> 1) << 2) + (view << 1) + (col & 1);
#pragma unroll
            for (int r = 0; r < 4; ++r) {
                int grow = row0 + wave * 32 + h * 16 + quad * 4 + r;
                if (grow < M) out[(size_t)grow * 256 + ci] = f2b(acc[h][g][r] + bv);
            }
        }
    }
}

// ---------------- fused dual-view aggregation + combine + relu ----------------
// Fixed-stride edge rows: dst d's edges at esrc[d*CAP .. d*CAP+cnt[d]).

__global__ __launch_bounds__(256) void agg_kernel(
        const unsigned* __restrict__ hcomb,       // [n][128] uints interleaved
        const int* __restrict__ cnt, const int* __restrict__ esrc,
        const float* __restrict__ dhis, const float* __restrict__ D_inv,
        float* __restrict__ out_q, float* __restrict__ out_p, int n) {
    int wave = threadIdx.x >> 6, lane = threadIdx.x & 63;
    int d = blockIdx.x * 4 + wave;
    if (d >= n) return;

    const uint2* hc2 = (const uint2*)hcomb;      // [n][64] uint2

    int e0 = d * CAP;
    int e1 = e0 + cnt[d];
    f32x2 a1 = {0.f, 0.f}, g1 = {0.f, 0.f};
    f32x2 a2 = {0.f, 0.f}, g2 = {0.f, 0.f};

#define EDGE_BODY(u, w) {                                         \
        f32x2 v1 = {blo((u).x), bhi((u).x)};                      \
        f32x2 v2 = {blo((u).y), bhi((u).y)};                      \
        f32x2 wv = {(w), (w)};                                    \
        a1 += v1; g1 = __builtin_elementwise_fma(v1, wv, g1);     \
        a2 += v2; g2 = __builtin_elementwise_fma(v2, wv, g2); }

    int e = e0;
    for (; e + 8 <= e1; e += 8) {
        int4 sa = *(const int4*)(esrc + e);
        int4 sb = *(const int4*)(esrc + e + 4);
        uint2 u0 = hc2[((size_t)sa.x << 6) + lane];
        uint2 u1 = hc2[((size_t)sa.y << 6) + lane];
        uint2 u2 = hc2[((size_t)sa.z << 6) + lane];
        uint2 u3 = hc2[((size_t)sa.w << 6) + lane];
        uint2 u4 = hc2[((size_t)sb.x << 6) + lane];
        uint2 u5 = hc2[((size_t)sb.y << 6) + lane];
        uint2 u6 = hc2[((size_t)sb.z << 6) + lane];
        uint2 u7 = hc2[((size_t)sb.w << 6) + lane];
        float w0 = dhis[sa.x], w1 = dhis[sa.y], w2 = dhis[sa.z], w3 = dhis[sa.w];
        float w4 = dhis[sb.x], w5 = dhis[sb.y], w6 = dhis[sb.z], w7 = dhis[sb.w];
        EDGE_BODY(u0, w0); EDGE_BODY(u1, w1);
        EDGE_BODY(u2, w2); EDGE_BODY(u3, w3);
        EDGE_BODY(u4, w4); EDGE_BODY(u5, w5);
        EDGE_BODY(u6, w6); EDGE_BODY(u7, w7);
    }
    for (; e + 4 <= e1; e += 4) {
        int4 sa = *(const int4*)(esrc + e);
        uint2 u0 = hc2[((size_t)sa.x << 6) + lane];
        uint2 u1 = hc2[((size_t)sa.y << 6) + lane];
        uint2 u2 = hc2[((size_t)sa.z << 6) + lane];
        uint2 u3 = hc2[((size_t)sa.w << 6) + lane];
        float w0 = dhis[sa.x], w1 = dhis[sa.y], w2 = dhis[sa.z], w3 = dhis[sa.w];
        EDGE_BODY(u0, w0); EDGE_BODY(u1, w1);
        EDGE_BODY(u2, w2); EDGE_BODY(u3, w3);
    }
    for (; e < e1; ++e) {
        int s = esrc[e];
        uint2 u = hc2[((size_t)s << 6) + lane];
        EDGE_BODY(u, dhis[s]);
    }
#undef EDGE_BODY

    float dh = dhis[d];
    float di = D_inv[d];
    float dh2 = dh * dh;
    f32x2 dhv = {dh, dh}, dh2v = {dh2, dh2}, div = {di, di};

    uint2 us = hc2[((size_t)d << 6) + lane];
    f32x2 s1 = {blo(us.x), bhi(us.x)};
    f32x2 s2 = {blo(us.y), bhi(us.y)};

    f32x2 o1 = __builtin_elementwise_fma(g1, dhv,
               __builtin_elementwise_fma(s1, dh2v, a2 * div));
    f32x2 o2 = __builtin_elementwise_fma(g2, dhv,
               __builtin_elementwise_fma(s2, dh2v, a1 * div));

    f32x2 zero = {0.f, 0.f};
    o1 = __builtin_elementwise_max(o1, zero);
    o2 = __builtin_elementwise_max(o2, zero);
    *(f32x2*)(out_q + (size_t)d * 384 + lane * 2) = o1;
    *(f32x2*)(out_p + (size_t)d * 384 + lane * 2) = o2;
}

// ---------------- launcher ----------------

extern "C" void kernel_launch(void* const* d_in, const int* in_sizes, int n_in,
                              void* d_out, int out_size, void* d_ws, size_t ws_size,
                              hipStream_t stream) {
    const float* x     = (const float*)d_in[0];
    const float* view2 = (const float*)d_in[1];
    const int*   eidx  = (const int*)d_in[2];
    const float* D_inv = (const float*)d_in[3];
    const float* W1 = (const float*)d_in[4];  const float* b1 = (const float*)d_in[5];
    const float* W2 = (const float*)d_in[6];  const float* b2 = (const float*)d_in[7];
    const float* W3 = (const float*)d_in[8];  const float* b3 = (const float*)d_in[9];
    const float* W4 = (const float*)d_in[10]; const float* b4 = (const float*)d_in[11];
    const float* W5 = (const float*)d_in[12]; const float* b5 = (const float*)d_in[13];
    const float* W6 = (const float*)d_in[14]; const float* b6 = (const float*)d_in[15];

    const int n = N_NODES;
    const int E = N_EDGES;
    const int* src  = eidx;
    const int* dstv = eidx + E;

    char* ws = (char*)d_ws;
    size_t off = 0;
    auto alloc = [&](size_t bytes) -> void* {
        void* p = ws + off;
        off += (bytes + 255) & ~(size_t)255;
        return p;
    };
    int*   cnt     = (int*)alloc((size_t)n * 4);
    float* dhis    = (float*)alloc((size_t)n * 4);
    int*   rank    = (int*)alloc((size_t)E * 4);
    int*   esrc    = (int*)alloc((size_t)n * CAP * 4);
    unsigned short* hcomb = (unsigned short*)alloc((size_t)n * 256 * 2);
    unsigned short* Wta   = (unsigned short*)alloc((size_t)NW_TOTAL * 2);

    unsigned short* Wt1 = Wta + 0;
    unsigned short* Wt4 = Wta + 24576;
    unsigned short* Wt2 = Wta + 49152;
    unsigned short* Wt3 = Wta + 65536;
    unsigned short* Wt5 = Wta + 81920;
    unsigned short* Wt6 = Wta + 98304;

    float* qb = (float*)d_out;
    float* pb = qb + (size_t)n * 384;

    // --- CSR-free build: prep+zero, hist(rank), fill(+dhis). No scan. ---
    int eblocks = (E + 255) / 256;
    prep_zero<<<(NW_TOTAL + 255) / 256, 256, 0, stream>>>(W1, W4, W2, W3, W5, W6,
                                                          Wta, cnt);
    hist_kernel<<<eblocks, 256, 0, stream>>>(dstv, E, cnt, rank);
    int nchunks = 1024;
    fill_sliced<<<nchunks * NSLICE, 256, 0, stream>>>(src, dstv, rank, cnt,
                                                      dhis, esrc, E, nchunks);

    dim3 ggrid((n + 127) / 128, 2);
    int ablocks = (n + 3) / 4;
    const unsigned* hc = (const unsigned*)hcomb;

    // --- layer 1 ---
    gemm_dual<<<ggrid, 256, 0, stream>>>(x, view2, D_IN, 192, 6, Wt1, Wt4, b1, b4, hcomb, n);
    agg_kernel<<<ablocks, 256, 0, stream>>>(hc, cnt, esrc, dhis, D_inv, qb + 0, pb + 0, n);

    // --- layer 2 ---
    gemm_dual<<<ggrid, 256, 0, stream>>>(qb, pb, 384, 128, 4, Wt2, Wt5, b2, b5, hcomb, n);
    agg_kernel<<<ablocks, 256, 0, stream>>>(hc, cnt, esrc, dhis, D_inv, qb + 128, pb + 128, n);

    // --- layer 3 ---
    gemm_dual<<<ggrid, 256, 0, stream>>>(qb + 128, pb + 128, 384, 128, 4, Wt3, Wt6, b3, b6, hcomb, n);
    agg_kernel<<<ablocks, 256, 0, stream>>>(hc, cnt, esrc, dhis, D_inv, qb + 256, pb + 256, n);
}

// Round 11
// 745.274 us; speedup vs baseline: 1.0420x; 1.0420x over previous
//
#include <hip/hip_runtime.h>

#define N_NODES 50000
#define N_EDGES 1600000
#define D_IN 192
#define D_HID 128

#define NSLICE 8
#define SLICE_SZ ((N_NODES + NSLICE - 1) / NSLICE)   // 6250 (dst slices for fill)

#define CAP 96                                        // fixed slots per node
#define NW_TOTAL 114688                               // Wt arena ushorts

typedef __bf16 bf16x8 __attribute__((ext_vector_type(8)));
typedef float f32x4 __attribute__((ext_vector_type(4)));
typedef float f32x2 __attribute__((ext_vector_type(2)));
typedef unsigned short u16x8 __attribute__((ext_vector_type(8)));

__device__ __forceinline__ unsigned short f2b(float x) {
    unsigned u = __builtin_bit_cast(unsigned, x);
    u += 0x7FFFu + ((u >> 16) & 1u);          // round-to-nearest-even
    return (unsigned short)(u >> 16);
}
__device__ __forceinline__ float blo(unsigned u) {   // low bf16 of packed pair
    return __builtin_bit_cast(float, u << 16);
}
__device__ __forceinline__ float bhi(unsigned u) {   // high bf16
    return __builtin_bit_cast(float, u & 0xFFFF0000u);
}
__device__ __forceinline__ bf16x8 pack8(float4 a, float4 b) {
    u16x8 t;
    t[0] = f2b(a.x); t[1] = f2b(a.y); t[2] = f2b(a.z); t[3] = f2b(a.w);
    t[4] = f2b(b.x); t[5] = f2b(b.y); t[6] = f2b(b.z); t[7] = f2b(b.w);
    return __builtin_bit_cast(bf16x8, t);
}

// ---------------- prep: weight transpose + zero cnt ----------------

__global__ __launch_bounds__(256) void prep_zero(
        const float* __restrict__ W1, const float* __restrict__ W4,
        const float* __restrict__ W2, const float* __restrict__ W3,
        const float* __restrict__ W5, const float* __restrict__ W6,
        unsigned short* __restrict__ Wt, int* __restrict__ cnt) {
    int idx = blockIdx.x * 256 + threadIdx.x;
    if (idx < N_NODES) cnt[idx] = 0;
    if (idx < NW_TOTAL) {
        const float* W; int K, base;
        if      (idx <  24576) { W = W1; K = 192; base = 0; }
        else if (idx <  49152) { W = W4; K = 192; base = 24576; }
        else if (idx <  65536) { W = W2; K = 128; base = 49152; }
        else if (idx <  81920) { W = W3; K = 128; base = 65536; }
        else if (idx <  98304) { W = W5; K = 128; base = 81920; }
        else                   { W = W6; K = 128; base = 98304; }
        int r = idx - base;
        int j = r / K, k = r - j * K;
        Wt[idx] = f2b(W[(size_t)k * 128 + j]);
    }
}

// ---------------- fused claim + scatter (no separate hist, no rank) ----------
// Block b -> dst slice (b%8), edge chunk (b/8). Each edge's dst is in exactly
// one slice, so the returning atomicAdd claims a unique slot; cnt ends as the
// in-degree. Slice-local esrc window (6250*CAP*4 = 2.4 MB) -> L2 write-combine.

__global__ __launch_bounds__(256) void fill_claim(
        const int* __restrict__ src, const int* __restrict__ dst,
        int* __restrict__ cnt, int* __restrict__ esrc, int E, int nchunks) {
    int slice = blockIdx.x & (NSLICE - 1);
    int chunk = blockIdx.x >> 3;
    int lo = slice * SLICE_SZ;
    int hi = lo + SLICE_SZ;
    int per = (E + nchunks - 1) / nchunks;
    int e0 = chunk * per;
    int e1 = min(e0 + per, E);
    for (int e = e0 + threadIdx.x; e < e1; e += 256) {
        int d = dst[e];
        if (d >= lo && d < hi) {
            int r = atomicAdd(&cnt[d], 1);
            esrc[d * CAP + r] = src[e];
        }
    }
}

// ---------------- dhis from final degrees ----------------

__global__ __launch_bounds__(256) void dhis_kernel(const int* __restrict__ cnt,
                                                   float* __restrict__ dhis) {
    int i = blockIdx.x * 256 + threadIdx.x;
    if (i < N_NODES) dhis[i] = rsqrtf((float)cnt[i] + 1.0f);
}

// ---------------- dual-view MFMA GEMM ----------------
// Block 256 thr = 4 waves, BM=128 (32 rows/wave, 2 row-frags). grid.y = view.
// B staged once into LDS in fragment-linear order (conflict-free b128 reads).
// A global->register per wave. Out interleaved: ci = (col>>1)*4+view*2+(col&1).

__global__ __launch_bounds__(256) void gemm_dual(
        const float* __restrict__ A0, const float* __restrict__ A1, int lda,
        int K, int ns,
        const unsigned short* __restrict__ Wt0, const unsigned short* __restrict__ Wt1,
        const float* __restrict__ bias0, const float* __restrict__ bias1,
        unsigned short* __restrict__ out, int M) {
    __shared__ __align__(16) unsigned short Wlds[192 * 128];   // up to 48 KB

    int view = blockIdx.y;
    const float* A = view ? A1 : A0;
    const unsigned short* Wt = view ? Wt1 : Wt0;
    const float* bias = view ? bias1 : bias0;

    int tid = threadIdx.x;

    int nfrag = ns * 512;
    for (int f = tid; f < nfrag; f += 256) {
        int lane = f & 63;
        int gk = f >> 6;
        int g = gk / ns, ks = gk - g * ns;
        int col = g * 16 + (lane & 15);
        int kpos = ks * 32 + (lane >> 4) * 8;
        *(bf16x8*)(Wlds + (size_t)f * 8) =
            *(const bf16x8*)(Wt + (size_t)col * K + kpos);
    }
    __syncthreads();

    int wave = tid >> 6, lane = tid & 63;
    int m = lane & 15, quad = lane >> 4;
    int row0 = blockIdx.x * 128;

    int rA0 = row0 + wave * 32 + m;
    int rA1 = rA0 + 16;
    int cA0 = rA0 < M ? rA0 : M - 1;
    int cA1 = rA1 < M ? rA1 : M - 1;
    const float* a0 = A + (size_t)cA0 * lda + quad * 8;
    const float* a1 = A + (size_t)cA1 * lda + quad * 8;

    f32x4 acc[2][8];
#pragma unroll
    for (int h = 0; h < 2; ++h)
#pragma unroll
        for (int g = 0; g < 8; ++g) acc[h][g] = (f32x4){0.f, 0.f, 0.f, 0.f};

    const bf16x8* wl = (const bf16x8*)Wlds;
    for (int ks = 0; ks < ns; ++ks) {
        float4 va = *(const float4*)(a0 + ks * 32);
        float4 vb = *(const float4*)(a0 + ks * 32 + 4);
        float4 vc = *(const float4*)(a1 + ks * 32);
        float4 vd = *(const float4*)(a1 + ks * 32 + 4);
        bf16x8 af0 = pack8(va, vb);
        bf16x8 af1 = pack8(vc, vd);
#pragma unroll
        for (int g = 0; g < 8; ++g) {
            bf16x8 bfr = wl[(g * ns + ks) * 64 + lane];
            acc[0][g] = __builtin_amdgcn_mfma_f32_16x16x32_bf16(af0, bfr, acc[0][g], 0, 0, 0);
            acc[1][g] = __builtin_amdgcn_mfma_f32_16x16x32_bf16(af1, bfr, acc[1][g], 0, 0, 0);
        }
    }

#pragma unroll
    for (int h = 0; h < 2; ++h) {
#pragma unroll
        for (int g = 0; g < 8; ++g) {
            int col = g * 16 + m;
            float bv = bias[col];
            int ci = ((col >> 1) << 2) + (view << 1) + (col & 1);
#pragma unroll
            for (int r = 0; r < 4; ++r) {
                int grow = row0 + wave * 32 + h * 16 + quad * 4 + r;
                if (grow < M) out[(size_t)grow * 256 + ci] = f2b(acc[h][g][r] + bv);
            }
        }
    }
}

// ---------------- fused dual-view aggregation + combine + relu ----------------
// Fixed-stride edge rows: dst d's edges at esrc[d*CAP .. d*CAP+cnt[d]).

__global__ __launch_bounds__(256) void agg_kernel(
        const unsigned* __restrict__ hcomb,       // [n][128] uints interleaved
        const int* __restrict__ cnt, const int* __restrict__ esrc,
        const float* __restrict__ dhis, const float* __restrict__ D_inv,
        float* __restrict__ out_q, float* __restrict__ out_p, int n) {
    int wave = threadIdx.x >> 6, lane = threadIdx.x & 63;
    int d = blockIdx.x * 4 + wave;
    if (d >= n) return;

    const uint2* hc2 = (const uint2*)hcomb;      // [n][64] uint2

    int e0 = d * CAP;
    int e1 = e0 + cnt[d];
    f32x2 a1 = {0.f, 0.f}, g1 = {0.f, 0.f};
    f32x2 a2 = {0.f, 0.f}, g2 = {0.f, 0.f};

#define EDGE_BODY(u, w) {                                         \
        f32x2 v1 = {blo((u).x), bhi((u).x)};                      \
        f32x2 v2 = {blo((u).y), bhi((u).y)};                      \
        f32x2 wv = {(w), (w)};                                    \
        a1 += v1; g1 = __builtin_elementwise_fma(v1, wv, g1);     \
        a2 += v2; g2 = __builtin_elementwise_fma(v2, wv, g2); }

    int e = e0;
    for (; e + 8 <= e1; e += 8) {
        int4 sa = *(const int4*)(esrc + e);
        int4 sb = *(const int4*)(esrc + e + 4);
        uint2 u0 = hc2[((size_t)sa.x << 6) + lane];
        uint2 u1 = hc2[((size_t)sa.y << 6) + lane];
        uint2 u2 = hc2[((size_t)sa.z << 6) + lane];
        uint2 u3 = hc2[((size_t)sa.w << 6) + lane];
        uint2 u4 = hc2[((size_t)sb.x << 6) + lane];
        uint2 u5 = hc2[((size_t)sb.y << 6) + lane];
        uint2 u6 = hc2[((size_t)sb.z << 6) + lane];
        uint2 u7 = hc2[((size_t)sb.w << 6) + lane];
        float w0 = dhis[sa.x], w1 = dhis[sa.y], w2 = dhis[sa.z], w3 = dhis[sa.w];
        float w4 = dhis[sb.x], w5 = dhis[sb.y], w6 = dhis[sb.z], w7 = dhis[sb.w];
        EDGE_BODY(u0, w0); EDGE_BODY(u1, w1);
        EDGE_BODY(u2, w2); EDGE_BODY(u3, w3);
        EDGE_BODY(u4, w4); EDGE_BODY(u5, w5);
        EDGE_BODY(u6, w6); EDGE_BODY(u7, w7);
    }
    for (; e + 4 <= e1; e += 4) {
        int4 sa = *(const int4*)(esrc + e);
        uint2 u0 = hc2[((size_t)sa.x << 6) + lane];
        uint2 u1 = hc2[((size_t)sa.y << 6) + lane];
        uint2 u2 = hc2[((size_t)sa.z << 6) + lane];
        uint2 u3 = hc2[((size_t)sa.w << 6) + lane];
        float w0 = dhis[sa.x], w1 = dhis[sa.y], w2 = dhis[sa.z], w3 = dhis[sa.w];
        EDGE_BODY(u0, w0); EDGE_BODY(u1, w1);
        EDGE_BODY(u2, w2); EDGE_BODY(u3, w3);
    }
    for (; e < e1; ++e) {
        int s = esrc[e];
        uint2 u = hc2[((size_t)s << 6) + lane];
        EDGE_BODY(u, dhis[s]);
    }
#undef EDGE_BODY

    float dh = dhis[d];
    float di = D_inv[d];
    float dh2 = dh * dh;
    f32x2 dhv = {dh, dh}, dh2v = {dh2, dh2}, div = {di, di};

    uint2 us = hc2[((size_t)d << 6) + lane];
    f32x2 s1 = {blo(us.x), bhi(us.x)};
    f32x2 s2 = {blo(us.y), bhi(us.y)};

    f32x2 o1 = __builtin_elementwise_fma(g1, dhv,
               __builtin_elementwise_fma(s1, dh2v, a2 * div));
    f32x2 o2 = __builtin_elementwise_fma(g2, dhv,
               __builtin_elementwise_fma(s2, dh2v, a1 * div));

    f32x2 zero = {0.f, 0.f};
    o1 = __builtin_elementwise_max(o1, zero);
    o2 = __builtin_elementwise_max(o2, zero);
    *(f32x2*)(out_q + (size_t)d * 384 + lane * 2) = o1;
    *(f32x2*)(out_p + (size_t)d * 384 + lane * 2) = o2;
}

// ---------------- launcher ----------------

extern "C" void kernel_launch(void* const* d_in, const int* in_sizes, int n_in,
                              void* d_out, int out_size, void* d_ws, size_t ws_size,
                              hipStream_t stream) {
    const float* x     = (const float*)d_in[0];
    const float* view2 = (const float*)d_in[1];
    const int*   eidx  = (const int*)d_in[2];
    const float* D_inv = (const float*)d_in[3];
    const float* W1 = (const float*)d_in[4];  const float* b1 = (const float*)d_in[5];
    const float* W2 = (const float*)d_in[6];  const float* b2 = (const float*)d_in[7];
    const float* W3 = (const float*)d_in[8];  const float* b3 = (const float*)d_in[9];
    const float* W4 = (const float*)d_in[10]; const float* b4 = (const float*)d_in[11];
    const float* W5 = (const float*)d_in[12]; const float* b5 = (const float*)d_in[13];
    const float* W6 = (const float*)d_in[14]; const float* b6 = (const float*)d_in[15];

    const int n = N_NODES;
    const int E = N_EDGES;
    const int* src  = eidx;
    const int* dstv = eidx + E;

    char* ws = (char*)d_ws;
    size_t off = 0;
    auto alloc = [&](size_t bytes) -> void* {
        void* p = ws + off;
        off += (bytes + 255) & ~(size_t)255;
        return p;
    };
    int*   cnt     = (int*)alloc((size_t)n * 4);
    float* dhis    = (float*)alloc((size_t)n * 4);
    int*   esrc    = (int*)alloc((size_t)n * CAP * 4);
    unsigned short* hcomb = (unsigned short*)alloc((size_t)n * 256 * 2);
    unsigned short* Wta   = (unsigned short*)alloc((size_t)NW_TOTAL * 2);

    unsigned short* Wt1 = Wta + 0;
    unsigned short* Wt4 = Wta + 24576;
    unsigned short* Wt2 = Wta + 49152;
    unsigned short* Wt3 = Wta + 65536;
    unsigned short* Wt5 = Wta + 81920;
    unsigned short* Wt6 = Wta + 98304;

    float* qb = (float*)d_out;
    float* pb = qb + (size_t)n * 384;

    // --- build: prep+zero, claim-fill (atomics fused), dhis. No hist/scan. ---
    prep_zero<<<(NW_TOTAL + 255) / 256, 256, 0, stream>>>(W1, W4, W2, W3, W5, W6,
                                                          Wta, cnt);
    int nchunks = 1024;
    fill_claim<<<nchunks * NSLICE, 256, 0, stream>>>(src, dstv, cnt, esrc, E, nchunks);
    dhis_kernel<<<(n + 255) / 256, 256, 0, stream>>>(cnt, dhis);

    dim3 ggrid((n + 127) / 128, 2);
    int ablocks = (n + 3) / 4;
    const unsigned* hc = (const unsigned*)hcomb;

    // --- layer 1 ---
    gemm_dual<<<ggrid, 256, 0, stream>>>(x, view2, D_IN, 192, 6, Wt1, Wt4, b1, b4, hcomb, n);
    agg_kernel<<<ablocks, 256, 0, stream>>>(hc, cnt, esrc, dhis, D_inv, qb + 0, pb + 0, n);

    // --- layer 2 ---
    gemm_dual<<<ggrid, 256, 0, stream>>>(qb, pb, 384, 128, 4, Wt2, Wt5, b2, b5, hcomb, n);
    agg_kernel<<<ablocks, 256, 0, stream>>>(hc, cnt, esrc, dhis, D_inv, qb + 128, pb + 128, n);

    // --- layer 3 ---
    gemm_dual<<<ggrid, 256, 0, stream>>>(qb + 128, pb + 128, 384, 128, 4, Wt3, Wt6, b3, b6, hcomb, n);
    agg_kernel<<<ablocks, 256, 0, stream>>>(hc, cnt, esrc, dhis, D_inv, qb + 256, pb + 256, n);
}